// Round 6
// baseline (178.543 us; speedup 1.0000x reference)
//
#include <hip/hip_runtime.h>
#include <hip/hip_bf16.h>

#define N_NODES 100000
#define N_EDGES 250000
#define EMB 32
#define TYPES 16
#define R2 100          // num relations (2*num_rels)
#define STRIPES 24      // stripes per relation for the MFMA kernels
#define SB 1024         // sort block size
#define NB ((N_EDGES + SB - 1) / SB)     // 245 sort blocks
#define NBN ((N_NODES + SB - 1) / SB)    // 98 node-scan blocks

typedef __attribute__((ext_vector_type(8))) short short8;   // 8 bf16 in 4 VGPRs
typedef __attribute__((ext_vector_type(4))) float f32x4;

// fp32 -> bf16 bits, round-to-nearest-even
__device__ __forceinline__ short f2bf(float f) {
    unsigned u = __float_as_uint(f);
    u = (u + 0x7fffu + ((u >> 16) & 1u)) >> 16;
    return (short)u;
}

// ---------------------------------------------------------------------------
// Pass 1: per-block relation histogram -> counts[b][r]; int in-degree dcnt.
__global__ __launch_bounds__(SB) void hist2_kernel(const int* __restrict__ etype,
                                                   const int* __restrict__ edge_dst,
                                                   int* __restrict__ counts,
                                                   int* __restrict__ dcnt) {
    __shared__ int lh[R2];
    int t = threadIdx.x, b = blockIdx.x;
    if (t < R2) lh[t] = 0;
    __syncthreads();
    int e = b * SB + t;
    if (e < N_EDGES) {
        atomicAdd(&lh[etype[e]], 1);                    // LDS atomic
        atomicAdd(&dcnt[edge_dst[e]], 1);               // 100k addrs: low contention
    }
    __syncthreads();
    if (t < R2) counts[b * R2 + t] = lh[t];
}

// Pass 2a: per relation, exclusive scan over blocks -> basem[b][r], total[r]
__global__ __launch_bounds__(256) void scanA_kernel(const int* __restrict__ counts,
                                                    int* __restrict__ basem,
                                                    int* __restrict__ total) {
    __shared__ int sd[256];
    int r = blockIdx.x, t = threadIdx.x;
    int v = (t < NB) ? counts[t * R2 + r] : 0;
    sd[t] = v;
    __syncthreads();
    for (int o = 1; o < 256; o <<= 1) {
        int x = (t >= o) ? sd[t - o] : 0;
        __syncthreads();
        sd[t] += x;
        __syncthreads();
    }
    if (t < NB) basem[t * R2 + r] = sd[t] - v;
    if (t == 255) total[r] = sd[t];
}

// Pass 2b: exclusive scan of 100 totals -> off[0..R2]
__global__ __launch_bounds__(128) void scanB_kernel(const int* __restrict__ total,
                                                    int* __restrict__ off) {
    __shared__ int sd[128];
    int t = threadIdx.x;
    int v = (t < R2) ? total[t] : 0;
    sd[t] = v;
    __syncthreads();
    for (int o = 1; o < 128; o <<= 1) {
        int x = (t >= o) ? sd[t - o] : 0;
        __syncthreads();
        sd[t] += x;
        __syncthreads();
    }
    if (t < R2) off[t] = sd[t] - v;
    if (t == R2 - 1) off[R2] = sd[t];
}

// ---------------------------------------------------------------------------
// Node-degree exclusive prefix scan (3 passes) -> dstart[0..N_NODES]
__global__ __launch_bounds__(SB) void scanN1_kernel(const int* __restrict__ dcnt,
                                                    int* __restrict__ dstart,
                                                    int* __restrict__ partials) {
    __shared__ int sd[SB];
    int t = threadIdx.x, b = blockIdx.x;
    int i = b * SB + t;
    int v = (i < N_NODES) ? dcnt[i] : 0;
    sd[t] = v;
    __syncthreads();
    for (int o = 1; o < SB; o <<= 1) {
        int x = (t >= o) ? sd[t - o] : 0;
        __syncthreads();
        sd[t] += x;
        __syncthreads();
    }
    if (i < N_NODES) dstart[i] = sd[t] - v;             // block-local exclusive
    if (t == SB - 1) partials[b] = sd[t];
}

__global__ __launch_bounds__(128) void scanN2_kernel(int* __restrict__ partials,
                                                     int* __restrict__ dstart) {
    __shared__ int sd[128];
    int t = threadIdx.x;
    int v = (t < NBN) ? partials[t] : 0;
    sd[t] = v;
    __syncthreads();
    for (int o = 1; o < 128; o <<= 1) {
        int x = (t >= o) ? sd[t - o] : 0;
        __syncthreads();
        sd[t] += x;
        __syncthreads();
    }
    if (t < NBN) partials[t] = sd[t] - v;               // exclusive block offsets
    if (t == 0) dstart[N_NODES] = N_EDGES;
}

__global__ __launch_bounds__(SB) void scanN3_kernel(int* __restrict__ dstart,
                                                    const int* __restrict__ partials) {
    int i = blockIdx.x * SB + threadIdx.x;
    if (i < N_NODES) dstart[i] += partials[blockIdx.x];
}

// ---------------------------------------------------------------------------
// Pass 3: scatter. relpos from LDS ranks (rel-sorted); pdst from per-dst cursor
// (dst-sorted slot each message row will be stored to).
__global__ __launch_bounds__(SB) void scatter2_kernel(const int* __restrict__ edge_src,
                                                      const int* __restrict__ edge_dst,
                                                      const int* __restrict__ etype,
                                                      const int* __restrict__ src_ids,
                                                      const int* __restrict__ basem,
                                                      const int* __restrict__ off,
                                                      const int* __restrict__ dstart,
                                                      int* __restrict__ dcur,
                                                      int* __restrict__ srcs,
                                                      int* __restrict__ sids,
                                                      int* __restrict__ pd1) {
    __shared__ int lh[R2];
    int t = threadIdx.x, b = blockIdx.x;
    if (t < R2) lh[t] = 0;
    __syncthreads();
    int e = b * SB + t;
    if (e < N_EDGES) {
        int r = etype[e];
        int rank = atomicAdd(&lh[r], 1);                // LDS atomic
        int relpos = off[r] + basem[b * R2 + r] + rank;
        int d = edge_dst[e];
        int drank = atomicAdd(&dcur[d], 1);             // avg depth 2.5
        int s = edge_src[e];
        srcs[relpos] = s;
        sids[relpos] = src_ids[s];
        pd1[relpos] = dstart[d] + drank;                // dst-sorted slot
    }
}

// ---------------------------------------------------------------------------
// Layer 1: per-relation tiles [16 edges x 32] = A[16x32] @ W1[r][32x32] via
// 2x mfma_f32_16x16x32_bf16; B-frags register-resident per stripe.
// Message rows stored (plain) to dst-sorted msg1 — NO atomics.
__global__ __launch_bounds__(64) void layer1_mfma_kernel(
        const float* __restrict__ entity,
        const float* __restrict__ W1, const int* __restrict__ off,
        const int* __restrict__ sids, const int* __restrict__ pd1,
        float* __restrict__ msg1) {
    int bid = blockIdx.x;
    int r = bid % R2;
    int stripe = bid / R2;
    int lo = off[r], hi = off[r + 1];
    int nG = (hi - lo + 15) >> 4;
    if (nG == 0) return;

    int lane = threadIdx.x;
    int n = lane & 15, q = lane >> 4;

    const float* Wr = W1 + (size_t)r * (EMB * EMB);
    short8 b0, b1;
#pragma unroll
    for (int j = 0; j < 8; ++j) {
        int k = q * 8 + j;
        b0[j] = f2bf(Wr[k * EMB + n]);
        b1[j] = f2bf(Wr[k * EMB + 16 + n]);
    }

    for (int g = stripe; g < nG; g += STRIPES) {
        int base = lo + g * 16;
        int cl = hi - base; if (cl > 16) cl = 16;
        int me = n < cl ? n : cl - 1;                   // clamp A row for tail
        int sid = sids[base + me];
        const float* hrow = entity + (size_t)sid * EMB + q * 8;
        float4 u = *(const float4*)hrow;
        float4 v = *(const float4*)(hrow + 4);
        short8 a;
        a[0] = f2bf(u.x); a[1] = f2bf(u.y); a[2] = f2bf(u.z); a[3] = f2bf(u.w);
        a[4] = f2bf(v.x); a[5] = f2bf(v.y); a[6] = f2bf(v.z); a[7] = f2bf(v.w);

        f32x4 c0 = {0.f, 0.f, 0.f, 0.f}, c1 = {0.f, 0.f, 0.f, 0.f};
        c0 = __builtin_amdgcn_mfma_f32_16x16x32_bf16(a, b0, c0, 0, 0, 0);
        c1 = __builtin_amdgcn_mfma_f32_16x16x32_bf16(a, b1, c1, 0, 0, 0);

        // C/D: col = lane&15 (=n), row = q*4+i (edge within tile)
#pragma unroll
        for (int i = 0; i < 4; ++i) {
            int row = q * 4 + i;
            if (row < cl) {
                int p = pd1[base + row];
                msg1[(size_t)p * EMB + n]      = c0[i];
                msg1[(size_t)p * EMB + 16 + n] = c1[i];
            }
        }
    }
}

// ---------------------------------------------------------------------------
// Segmented mean + relu: h1[n][c] = relu( mean(msg1[dstart[n]:dstart[n+1], c]) )
// Streaming: segments are contiguous; adjacent threads share rows (coalesced).
__global__ void reduce1_kernel(const float* __restrict__ msg1,
                               const int* __restrict__ dstart,
                               float* __restrict__ h1) {
    int t = blockIdx.x * blockDim.x + threadIdx.x;      // over N_NODES*EMB
    if (t >= N_NODES * EMB) return;
    int nn = t >> 5, c = t & 31;
    int s = dstart[nn], e = dstart[nn + 1];
    float sum = 0.f;
    for (int k = s; k < e; ++k) sum += msg1[(size_t)k * EMB + c];
    float inv = 1.0f / fmaxf((float)(e - s), 1.0f);
    h1[t] = fmaxf(sum * inv, 0.f);
}

// ---------------------------------------------------------------------------
// Layer 2: [16 edges x 16] = A[16x32] @ W2[r][32x16], one MFMA; store to msg2.
__global__ __launch_bounds__(64) void layer2_mfma_kernel(
        const float* __restrict__ h1, const float* __restrict__ W2,
        const int* __restrict__ off, const int* __restrict__ srcs,
        const int* __restrict__ pd1, float* __restrict__ msg2) {
    int bid = blockIdx.x;
    int r = bid % R2;
    int stripe = bid / R2;
    int lo = off[r], hi = off[r + 1];
    int nG = (hi - lo + 15) >> 4;
    if (nG == 0) return;

    int lane = threadIdx.x;
    int n = lane & 15, q = lane >> 4;

    const float* Wr = W2 + (size_t)r * (EMB * TYPES);
    short8 b;
#pragma unroll
    for (int j = 0; j < 8; ++j) {
        int k = q * 8 + j;
        b[j] = f2bf(Wr[k * TYPES + n]);
    }

    for (int g = stripe; g < nG; g += STRIPES) {
        int base = lo + g * 16;
        int cl = hi - base; if (cl > 16) cl = 16;
        int me = n < cl ? n : cl - 1;
        int s = srcs[base + me];
        const float* hrow = h1 + (size_t)s * EMB + q * 8;
        float4 u = *(const float4*)hrow;
        float4 v = *(const float4*)(hrow + 4);
        short8 a;
        a[0] = f2bf(u.x); a[1] = f2bf(u.y); a[2] = f2bf(u.z); a[3] = f2bf(u.w);
        a[4] = f2bf(v.x); a[5] = f2bf(v.y); a[6] = f2bf(v.z); a[7] = f2bf(v.w);

        f32x4 c = {0.f, 0.f, 0.f, 0.f};
        c = __builtin_amdgcn_mfma_f32_16x16x32_bf16(a, b, c, 0, 0, 0);

#pragma unroll
        for (int i = 0; i < 4; ++i) {
            int row = q * 4 + i;
            if (row < cl) {
                int p = pd1[base + row];
                msg2[(size_t)p * TYPES + n] = c[i];
            }
        }
    }
}

// ---------------------------------------------------------------------------
// Segmented mean + PonderNet head, fused. One thread per node.
// out = [ y (=h2, twice, [2,N,16]) ; p ([lam,1-lam],[2,N]) ]  fp32
__global__ void reduce2_head_kernel(const float* __restrict__ msg2,
                                    const int* __restrict__ dstart,
                                    const float* __restrict__ lw,
                                    const float* __restrict__ lb,
                                    float* __restrict__ out) {
    int nn = blockIdx.x * blockDim.x + threadIdx.x;
    if (nn >= N_NODES) return;
    int s = dstart[nn], e = dstart[nn + 1];

    float4 a0 = {0,0,0,0}, a1 = {0,0,0,0}, a2 = {0,0,0,0}, a3 = {0,0,0,0};
    for (int k = s; k < e; ++k) {
        const float4* row = (const float4*)(msg2 + (size_t)k * TYPES);
        float4 r0 = row[0], r1 = row[1], r2 = row[2], r3 = row[3];
        a0.x += r0.x; a0.y += r0.y; a0.z += r0.z; a0.w += r0.w;
        a1.x += r1.x; a1.y += r1.y; a1.z += r1.z; a1.w += r1.w;
        a2.x += r2.x; a2.y += r2.y; a2.z += r2.z; a2.w += r2.w;
        a3.x += r3.x; a3.y += r3.y; a3.z += r3.z; a3.w += r3.w;
    }
    float inv = 1.0f / fmaxf((float)(e - s), 1.0f);
    float h[TYPES];
    h[0]=a0.x*inv; h[1]=a0.y*inv; h[2]=a0.z*inv; h[3]=a0.w*inv;
    h[4]=a1.x*inv; h[5]=a1.y*inv; h[6]=a1.z*inv; h[7]=a1.w*inv;
    h[8]=a2.x*inv; h[9]=a2.y*inv; h[10]=a2.z*inv; h[11]=a2.w*inv;
    h[12]=a3.x*inv; h[13]=a3.y*inv; h[14]=a3.z*inv; h[15]=a3.w*inv;

    float dot = 0.f;
#pragma unroll
    for (int j = 0; j < TYPES; ++j) dot += h[j] * lw[j];
    dot += lb[0];
    float lam = 1.0f / (1.0f + expf(-dot));

    float4* y0 = (float4*)(out + (size_t)nn * TYPES);
    float4* y1 = (float4*)(out + (size_t)N_NODES * TYPES + (size_t)nn * TYPES);
#pragma unroll
    for (int j = 0; j < 4; ++j) {
        float4 v = { h[4*j], h[4*j+1], h[4*j+2], h[4*j+3] };
        y0[j] = v; y1[j] = v;
    }
    out[(size_t)2 * N_NODES * TYPES + nn] = lam;
    out[(size_t)2 * N_NODES * TYPES + N_NODES + nn] = 1.0f - lam;
}

// ---------------------------------------------------------------------------
extern "C" void kernel_launch(void* const* d_in, const int* in_sizes, int n_in,
                              void* d_out, int out_size, void* d_ws, size_t ws_size,
                              hipStream_t stream) {
    const float* entity = (const float*)d_in[0];
    const float* W1     = (const float*)d_in[1];
    const float* W2     = (const float*)d_in[2];
    const float* lw     = (const float*)d_in[3];
    const float* lb     = (const float*)d_in[4];
    const int* src_ids  = (const int*)d_in[5];
    const int* edge_src = (const int*)d_in[6];
    const int* edge_dst = (const int*)d_in[7];
    const int* etype    = (const int*)d_in[8];
    float* out = (float*)d_out;

    // ws layout (4B units):
    // dcnt[100k] | dcur[100k]   <- only region needing zero-init
    // | dstart[100k+8] | partials[128] | counts[NB*R2] | basem[NB*R2]
    // | total[128] | off[128] | srcs[250k] | sids[250k] | pd1[250k]
    // | msg1[250k*32] | msg2[250k*16] | h1[100k*32]
    int* dcnt    = (int*)d_ws;
    int* dcur    = dcnt + N_NODES;
    int* dstart  = dcur + N_NODES;
    int* partials= dstart + N_NODES + 8;
    int* counts  = partials + 128;
    int* basem   = counts + NB * R2;
    int* total   = basem + NB * R2;
    int* off     = total + 128;
    int* srcs    = off + 128;
    int* sids    = srcs + N_EDGES;
    int* pd1     = sids + N_EDGES;
    float* msg1  = (float*)(pd1 + N_EDGES);
    float* msg2  = msg1 + (size_t)N_EDGES * EMB;
    float* h1    = msg2 + (size_t)N_EDGES * TYPES;

    hipMemsetAsync(d_ws, 0, 2 * N_NODES * sizeof(int), stream);  // dcnt+dcur only

    const int B = 256;
    hist2_kernel<<<NB, SB, 0, stream>>>(etype, edge_dst, counts, dcnt);
    scanA_kernel<<<R2, 256, 0, stream>>>(counts, basem, total);
    scanB_kernel<<<1, 128, 0, stream>>>(total, off);
    scanN1_kernel<<<NBN, SB, 0, stream>>>(dcnt, dstart, partials);
    scanN2_kernel<<<1, 128, 0, stream>>>(partials, dstart);
    scanN3_kernel<<<NBN, SB, 0, stream>>>(dstart, partials);
    scatter2_kernel<<<NB, SB, 0, stream>>>(edge_src, edge_dst, etype, src_ids,
                                           basem, off, dstart, dcur, srcs, sids, pd1);
    layer1_mfma_kernel<<<R2 * STRIPES, 64, 0, stream>>>(entity, W1, off, sids, pd1, msg1);
    reduce1_kernel<<<(N_NODES * EMB + B - 1) / B, B, 0, stream>>>(msg1, dstart, h1);
    layer2_mfma_kernel<<<R2 * STRIPES, 64, 0, stream>>>(h1, W2, off, srcs, pd1, msg2);
    reduce2_head_kernel<<<(N_NODES + B - 1) / B, B, 0, stream>>>(msg2, dstart, lw, lb, out);
}

// Round 8
// 165.405 us; speedup vs baseline: 1.0794x; 1.0794x over previous
//
#include <hip/hip_runtime.h>
#include <hip/hip_bf16.h>

#define N_NODES 100000
#define N_EDGES 250000
#define EMB 32
#define TYPES 16
#define R2 100          // num relations
#define SB 1024
#define NB ((N_EDGES + SB - 1) / SB)    // 245
#define NBN ((N_NODES + SB - 1) / SB)   // 98
#define S1 64           // stripes per relation, layer 1
#define S2 64           // stripes per relation, layer 2

typedef __attribute__((ext_vector_type(8))) short short8;
typedef __attribute__((ext_vector_type(4))) float f32x4;

// fp32 -> bf16 bits, round-to-nearest-even
__device__ __forceinline__ unsigned short f2bf_u(float f) {
    unsigned u = __float_as_uint(f);
    u = (u + 0x7fffu + ((u >> 16) & 1u)) >> 16;
    return (unsigned short)u;
}

// ---------------------------------------------------------------------------
// Pass 1: per-block relation histogram -> counts[b][r]; dcnt atomics;
// fused: entity -> bf16 (2 threads per row, 64B each, coalesced).
__global__ __launch_bounds__(SB) void hist_conv_kernel(
        const int* __restrict__ etype, const int* __restrict__ edge_dst,
        const float* __restrict__ entity,
        int* __restrict__ counts, int* __restrict__ dcnt,
        unsigned short* __restrict__ ent_bf) {
    __shared__ int lh[R2];
    int t = threadIdx.x, b = blockIdx.x;
    if (t < R2) lh[t] = 0;
    __syncthreads();
    int e = b * SB + t;
    if (e < N_EDGES) {
        atomicAdd(&lh[etype[e]], 1);
        atomicAdd(&dcnt[edge_dst[e]], 1);
    }
    if (e < 2 * N_NODES) {
        int node = e >> 1, half = e & 1;
        const float4* src = (const float4*)(entity + (size_t)node * EMB + half * 16);
        ushort4* dst = (ushort4*)(ent_bf + (size_t)node * EMB + half * 16);
#pragma unroll
        for (int i = 0; i < 4; ++i) {
            float4 v = src[i];
            ushort4 o = { f2bf_u(v.x), f2bf_u(v.y), f2bf_u(v.z), f2bf_u(v.w) };
            dst[i] = o;
        }
    }
    __syncthreads();
    if (t < R2) counts[b * R2 + t] = lh[t];
}

// ---------------------------------------------------------------------------
// Node-degree block-local exclusive scan -> dstart (local), partials[b] = block sum
__global__ __launch_bounds__(SB) void scanN1_kernel(const int* __restrict__ dcnt,
                                                    int* __restrict__ dstart,
                                                    int* __restrict__ partials) {
    __shared__ int sd[SB];
    int t = threadIdx.x, b = blockIdx.x;
    int i = b * SB + t;
    int v = (i < N_NODES) ? dcnt[i] : 0;
    sd[t] = v;
    __syncthreads();
    for (int o = 1; o < SB; o <<= 1) {
        int x = (t >= o) ? sd[t - o] : 0;
        __syncthreads();
        sd[t] += x;
        __syncthreads();
    }
    if (i < N_NODES) dstart[i] = sd[t] - v;
    if (t == SB - 1) partials[b] = sd[t];
}

// ---------------------------------------------------------------------------
// Per relation: exclusive scan of counts over blocks -> basem, total;
// fused: pack W1/W2 into MFMA-fragment order (bf16).
__global__ __launch_bounds__(256) void scanA_packW_kernel(
        const int* __restrict__ counts, int* __restrict__ basem,
        int* __restrict__ total,
        const float* __restrict__ W1, const float* __restrict__ W2,
        unsigned short* __restrict__ pw1, unsigned short* __restrict__ pw2) {
    __shared__ int sd[256];
    int r = blockIdx.x, t = threadIdx.x;
    int v = (t < NB) ? counts[t * R2 + r] : 0;
    sd[t] = v;
    __syncthreads();
    for (int o = 1; o < 256; o <<= 1) {
        int x = (t >= o) ? sd[t - o] : 0;
        __syncthreads();
        sd[t] += x;
        __syncthreads();
    }
    if (t < NB) basem[t * R2 + r] = sd[t] - v;
    if (t == 255) total[r] = sd[t];

    // pw1[r][lane][0..7]=B0 (col n), [8..15]=B1 (col 16+n); k = q*8+j
    const float* Wr1 = W1 + (size_t)r * (EMB * EMB);
    for (int idx = t; idx < 64 * 16; idx += 256) {
        int l = idx >> 4, j = idx & 15;
        int n = l & 15, q = l >> 4;
        int k = q * 8 + (j & 7);
        int col = (j < 8) ? n : (16 + n);
        pw1[(size_t)r * 1024 + idx] = f2bf_u(Wr1[k * EMB + col]);
    }
    const float* Wr2 = W2 + (size_t)r * (EMB * TYPES);
    for (int idx = t; idx < 64 * 8; idx += 256) {
        int l = idx >> 3, j = idx & 7;
        int n = l & 15, q = l >> 4;
        int k = q * 8 + j;
        pw2[(size_t)r * 512 + idx] = f2bf_u(Wr2[k * TYPES + n]);
    }
}

// ---------------------------------------------------------------------------
// Two independent single-block scans: block0 = relation offsets, block1 = node partials.
__global__ __launch_bounds__(256) void scanB2_kernel(const int* __restrict__ total,
                                                     int* __restrict__ off,
                                                     int* __restrict__ partials) {
    __shared__ int sd[256];
    int t = threadIdx.x;
    if (blockIdx.x == 0) {
        int v = (t < R2) ? total[t] : 0;
        sd[t] = v;
        __syncthreads();
        for (int o = 1; o < 256; o <<= 1) {
            int x = (t >= o) ? sd[t - o] : 0; __syncthreads();
            sd[t] += x; __syncthreads();
        }
        if (t < R2) off[t] = sd[t] - v;
        if (t == R2 - 1) off[R2] = sd[t];
    } else {
        int v = (t < NBN) ? partials[t] : 0;
        sd[t] = v;
        __syncthreads();
        for (int o = 1; o < 256; o <<= 1) {
            int x = (t >= o) ? sd[t - o] : 0; __syncthreads();
            sd[t] += x; __syncthreads();
        }
        if (t < NBN) partials[t] = sd[t] - v;          // exclusive, in place
    }
}

// ---------------------------------------------------------------------------
// Scatter: relpos via LDS ranks; dst slot via dcur atomic; fused A-row packing
// (gather ent_bf[sid] -> packA[relpos], hidden by 250k-thread TLP).
__global__ __launch_bounds__(SB) void scatter_pack_kernel(
        const int* __restrict__ edge_src, const int* __restrict__ edge_dst,
        const int* __restrict__ etype, const int* __restrict__ src_ids,
        const int* __restrict__ basem, const int* __restrict__ off,
        const int* __restrict__ dstart, const int* __restrict__ partials,
        int* __restrict__ dcur, const unsigned short* __restrict__ ent_bf,
        int* __restrict__ srcs, int* __restrict__ pd1,
        unsigned short* __restrict__ packA) {
    __shared__ int lh[R2];
    int t = threadIdx.x, b = blockIdx.x;
    if (t < R2) lh[t] = 0;
    __syncthreads();
    int e = b * SB + t;
    if (e >= N_EDGES) return;
    int r = etype[e];
    int rank = atomicAdd(&lh[r], 1);
    int relpos = off[r] + basem[b * R2 + r] + rank;
    int d = edge_dst[e];
    int drank = atomicAdd(&dcur[d], 1);
    int s = edge_src[e];
    srcs[relpos] = s;
    pd1[relpos] = dstart[d] + partials[d >> 10] + drank;
    int sid = src_ids[s];
    const ushort4* src4 = (const ushort4*)(ent_bf + (size_t)sid * EMB);
    ushort4* dst4 = (ushort4*)(packA + (size_t)relpos * EMB);
#pragma unroll
    for (int i = 0; i < 8; ++i) dst4[i] = src4[i];
}

// ---------------------------------------------------------------------------
// Layer 1: fully-coalesced stream of packA tiles; register B-frags; 2 MFMA/tile;
// rows stored to dst-sorted msg1 (no atomics, no LDS, no shfl).
__global__ __launch_bounds__(64) void layer1_kernel(
        const unsigned short* __restrict__ packA,
        const unsigned short* __restrict__ pw1,
        const int* __restrict__ off, const int* __restrict__ pd1,
        float* __restrict__ msg1) {
    int r = blockIdx.x % R2, stripe = blockIdx.x / R2;
    int lo = off[r], hi = off[r + 1];
    int nT = (hi - lo + 15) >> 4;
    int lane = threadIdx.x;
    int n = lane & 15, q = lane >> 4;
    short8 b0 = *(const short8*)(pw1 + (size_t)r * 1024 + lane * 16);
    short8 b1 = *(const short8*)(pw1 + (size_t)r * 1024 + lane * 16 + 8);
    int alane = n * EMB + q * 8;
    for (int g = stripe; g < nT; g += S1) {
        int base = lo + g * 16;
        short8 a = *(const short8*)(packA + (size_t)base * EMB + alane);  // 1KB/tile coalesced
        f32x4 c0 = {0.f,0.f,0.f,0.f}, c1 = {0.f,0.f,0.f,0.f};
        c0 = __builtin_amdgcn_mfma_f32_16x16x32_bf16(a, b0, c0, 0, 0, 0);
        c1 = __builtin_amdgcn_mfma_f32_16x16x32_bf16(a, b1, c1, 0, 0, 0);
        int cl = hi - base;
#pragma unroll
        for (int i = 0; i < 4; ++i) {
            int row = q * 4 + i;
            if (row < cl) {
                int p = pd1[base + row];
                msg1[(size_t)p * EMB + n]      = c0[i];
                msg1[(size_t)p * EMB + 16 + n] = c1[i];
            }
        }
    }
}

// ---------------------------------------------------------------------------
// Segmented mean + relu -> h1 in bf16 (packed 2 cols per u32 store).
__global__ void reduce1_kernel(const float* __restrict__ msg1,
                               const int* __restrict__ dstart,
                               const int* __restrict__ partials,
                               const int* __restrict__ dcnt,
                               unsigned int* __restrict__ h1bf) {
    int t = blockIdx.x * blockDim.x + threadIdx.x;   // over N_NODES*16
    if (t >= N_NODES * 16) return;
    int nn = t >> 4, cp = t & 15;
    int s = dstart[nn] + partials[nn >> 10];
    int cnt = dcnt[nn];
    float sx = 0.f, sy = 0.f;
    for (int k = 0; k < cnt; ++k) {
        float2 v = *(const float2*)(msg1 + (size_t)(s + k) * EMB + cp * 2);
        sx += v.x; sy += v.y;
    }
    float inv = 1.0f / fmaxf((float)cnt, 1.0f);
    unsigned lo = f2bf_u(fmaxf(sx * inv, 0.f));
    unsigned hi = f2bf_u(fmaxf(sy * inv, 0.f));
    h1bf[t] = lo | (hi << 16);
}

// ---------------------------------------------------------------------------
// Layer 2: gather bf16 h1 rows (16B/lane), 1 MFMA/tile, store msg2 dst-sorted.
__global__ __launch_bounds__(64) void layer2_kernel(
        const unsigned short* __restrict__ h1bf,
        const unsigned short* __restrict__ pw2,
        const int* __restrict__ off, const int* __restrict__ srcs,
        const int* __restrict__ pd1, float* __restrict__ msg2) {
    int r = blockIdx.x % R2, stripe = blockIdx.x / R2;
    int lo = off[r], hi = off[r + 1];
    int nT = (hi - lo + 15) >> 4;
    int lane = threadIdx.x;
    int n = lane & 15, q = lane >> 4;
    short8 b = *(const short8*)(pw2 + (size_t)r * 512 + lane * 8);
    for (int g = stripe; g < nT; g += S2) {
        int base = lo + g * 16;
        int cl = hi - base;
        int me = n < cl ? n : cl - 1;                  // keep srcs index in-range
        int s = srcs[base + me];
        short8 a = *(const short8*)(h1bf + (size_t)s * EMB + q * 8);
        f32x4 c = {0.f,0.f,0.f,0.f};
        c = __builtin_amdgcn_mfma_f32_16x16x32_bf16(a, b, c, 0, 0, 0);
#pragma unroll
        for (int i = 0; i < 4; ++i) {
            int row = q * 4 + i;
            if (row < cl) {
                int p = pd1[base + row];
                msg2[(size_t)p * TYPES + n] = c[i];
            }
        }
    }
}

// ---------------------------------------------------------------------------
// Segmented mean + PonderNet head, fused; writes final output.
__global__ void reduce2_head_kernel(const float* __restrict__ msg2,
                                    const int* __restrict__ dstart,
                                    const int* __restrict__ partials,
                                    const int* __restrict__ dcnt,
                                    const float* __restrict__ lw,
                                    const float* __restrict__ lb,
                                    float* __restrict__ out) {
    int nn = blockIdx.x * blockDim.x + threadIdx.x;
    if (nn >= N_NODES) return;
    int s = dstart[nn] + partials[nn >> 10];
    int cnt = dcnt[nn];

    float4 a0 = {0,0,0,0}, a1 = {0,0,0,0}, a2 = {0,0,0,0}, a3 = {0,0,0,0};
    for (int k = 0; k < cnt; ++k) {
        const float4* row = (const float4*)(msg2 + (size_t)(s + k) * TYPES);
        float4 r0 = row[0], r1 = row[1], r2 = row[2], r3 = row[3];
        a0.x += r0.x; a0.y += r0.y; a0.z += r0.z; a0.w += r0.w;
        a1.x += r1.x; a1.y += r1.y; a1.z += r1.z; a1.w += r1.w;
        a2.x += r2.x; a2.y += r2.y; a2.z += r2.z; a2.w += r2.w;
        a3.x += r3.x; a3.y += r3.y; a3.z += r3.z; a3.w += r3.w;
    }
    float inv = 1.0f / fmaxf((float)cnt, 1.0f);
    float h[TYPES];
    h[0]=a0.x*inv; h[1]=a0.y*inv; h[2]=a0.z*inv; h[3]=a0.w*inv;
    h[4]=a1.x*inv; h[5]=a1.y*inv; h[6]=a1.z*inv; h[7]=a1.w*inv;
    h[8]=a2.x*inv; h[9]=a2.y*inv; h[10]=a2.z*inv; h[11]=a2.w*inv;
    h[12]=a3.x*inv; h[13]=a3.y*inv; h[14]=a3.z*inv; h[15]=a3.w*inv;

    float dot = 0.f;
#pragma unroll
    for (int j = 0; j < TYPES; ++j) dot += h[j] * lw[j];
    dot += lb[0];
    float lam = 1.0f / (1.0f + expf(-dot));

    float4* y0 = (float4*)(out + (size_t)nn * TYPES);
    float4* y1 = (float4*)(out + (size_t)N_NODES * TYPES + (size_t)nn * TYPES);
#pragma unroll
    for (int j = 0; j < 4; ++j) {
        float4 v = { h[4*j], h[4*j+1], h[4*j+2], h[4*j+3] };
        y0[j] = v; y1[j] = v;
    }
    out[(size_t)2 * N_NODES * TYPES + nn] = lam;
    out[(size_t)2 * N_NODES * TYPES + N_NODES + nn] = 1.0f - lam;
}

// ---------------------------------------------------------------------------
extern "C" void kernel_launch(void* const* d_in, const int* in_sizes, int n_in,
                              void* d_out, int out_size, void* d_ws, size_t ws_size,
                              hipStream_t stream) {
    const float* entity = (const float*)d_in[0];
    const float* W1     = (const float*)d_in[1];
    const float* W2     = (const float*)d_in[2];
    const float* lw     = (const float*)d_in[3];
    const float* lb     = (const float*)d_in[4];
    const int* src_ids  = (const int*)d_in[5];
    const int* edge_src = (const int*)d_in[6];
    const int* edge_dst = (const int*)d_in[7];
    const int* etype    = (const int*)d_in[8];
    float* out = (float*)d_out;

    // ws layout (u32 units, all 16B aligned)
    unsigned int* W = (unsigned int*)d_ws;
    int* dcnt      = (int*)(W + 0);            // 100000   (zeroed)
    int* dcur      = (int*)(W + 100000);       // 100000   (zeroed)
    int* dstart    = (int*)(W + 200000);       // 100008
    int* partials  = (int*)(W + 300008);       // 128
    int* counts    = (int*)(W + 300136);       // 24500
    int* basem     = (int*)(W + 324636);       // 24500
    int* total     = (int*)(W + 349136);       // 128
    int* off       = (int*)(W + 349264);       // 128
    int* srcs      = (int*)(W + 349392);       // 250000
    int* pd1       = (int*)(W + 599392);       // 250000
    unsigned short* ent_bf = (unsigned short*)(W + 849392);   // 1.6M u32
    unsigned short* packA  = (unsigned short*)(W + 2449392);  // 4M u32
    unsigned short* pw1    = (unsigned short*)(W + 6449392);  // 51200 u32
    unsigned short* pw2    = (unsigned short*)(W + 6500592);  // 25600 u32
    float* msg1    = (float*)(W + 6526192);    // 8M
    unsigned int* h1bf = (unsigned int*)(W + 14526192);       // 1.6M
    float* msg2    = (float*)(W + 16126192);   // 4M  -> total ~80.5 MB

    (void)hipMemsetAsync(d_ws, 0, 200000 * sizeof(int), stream);   // dcnt + dcur

    hist_conv_kernel<<<NB, SB, 0, stream>>>(etype, edge_dst, entity,
                                            counts, dcnt, ent_bf);
    scanN1_kernel<<<NBN, SB, 0, stream>>>(dcnt, dstart, partials);
    scanA_packW_kernel<<<R2, 256, 0, stream>>>(counts, basem, total, W1, W2, pw1, pw2);
    scanB2_kernel<<<2, 256, 0, stream>>>(total, off, partials);
    scatter_pack_kernel<<<NB, SB, 0, stream>>>(edge_src, edge_dst, etype, src_ids,
                                               basem, off, dstart, partials, dcur,
                                               ent_bf, srcs, pd1, packA);
    layer1_kernel<<<R2 * S1, 64, 0, stream>>>(packA, pw1, off, pd1, msg1);
    reduce1_kernel<<<(N_NODES * 16 + 255) / 256, 256, 0, stream>>>(
        msg1, dstart, partials, dcnt, h1bf);
    layer2_kernel<<<R2 * S2, 64, 0, stream>>>((const unsigned short*)h1bf, pw2,
                                              off, srcs, pd1, msg2);
    reduce2_head_kernel<<<(N_NODES + 255) / 256, 256, 0, stream>>>(
        msg2, dstart, partials, dcnt, lw, lb, out);
}

// Round 9
// 151.730 us; speedup vs baseline: 1.1767x; 1.0901x over previous
//
#include <hip/hip_runtime.h>
#include <hip/hip_bf16.h>

#define N_NODES 100000
#define N_EDGES 250000
#define EMB 32
#define TYPES 16
#define R2 100          // num relations
#define SB 1024
#define NB ((N_EDGES + SB - 1) / SB)    // 245
#define NBN ((N_NODES + SB - 1) / SB)   // 98
#define S1 64           // stripes per relation, layer 1
#define S2 64           // stripes per relation, layer 2

typedef __attribute__((ext_vector_type(8))) short short8;
typedef __attribute__((ext_vector_type(4))) float f32x4;

// fp32 -> bf16 bits, round-to-nearest-even
__device__ __forceinline__ unsigned short f2bf_u(float f) {
    unsigned u = __float_as_uint(f);
    u = (u + 0x7fffu + ((u >> 16) & 1u)) >> 16;
    return (unsigned short)u;
}
// unpack bf16 pair from u32
__device__ __forceinline__ float bfl(unsigned u) { return __uint_as_float(u << 16); }
__device__ __forceinline__ float bfh(unsigned u) { return __uint_as_float(u & 0xffff0000u); }

// ---------------------------------------------------------------------------
// Pass 1: per-block relation histogram -> counts[b][r]; dcnt atomics;
// fused: entity -> bf16 (2 threads per row, coalesced).
__global__ __launch_bounds__(SB) void hist_conv_kernel(
        const int* __restrict__ etype, const int* __restrict__ edge_dst,
        const float* __restrict__ entity,
        int* __restrict__ counts, int* __restrict__ dcnt,
        unsigned short* __restrict__ ent_bf) {
    __shared__ int lh[R2];
    int t = threadIdx.x, b = blockIdx.x;
    if (t < R2) lh[t] = 0;
    __syncthreads();
    int e = b * SB + t;
    if (e < N_EDGES) {
        atomicAdd(&lh[etype[e]], 1);
        atomicAdd(&dcnt[edge_dst[e]], 1);
    }
    if (e < 2 * N_NODES) {
        int node = e >> 1, half = e & 1;
        const float4* src = (const float4*)(entity + (size_t)node * EMB + half * 16);
        ushort4* dst = (ushort4*)(ent_bf + (size_t)node * EMB + half * 16);
#pragma unroll
        for (int i = 0; i < 4; ++i) {
            float4 v = src[i];
            ushort4 o = { f2bf_u(v.x), f2bf_u(v.y), f2bf_u(v.z), f2bf_u(v.w) };
            dst[i] = o;
        }
    }
    __syncthreads();
    if (t < R2) counts[b * R2 + t] = lh[t];
}

// ---------------------------------------------------------------------------
// Fused scan kernel. Blocks [0,NBN): node-degree block-local exclusive scan.
// Blocks [NBN, NBN+R2): per-relation scan of counts over blocks + W pack.
__global__ __launch_bounds__(SB) void scan_fused_kernel(
        const int* __restrict__ dcnt, int* __restrict__ dstart,
        int* __restrict__ partials,
        const int* __restrict__ counts, int* __restrict__ basem,
        int* __restrict__ total,
        const float* __restrict__ W1, const float* __restrict__ W2,
        unsigned short* __restrict__ pw1, unsigned short* __restrict__ pw2) {
    __shared__ int sd[SB];
    int t = threadIdx.x, b = blockIdx.x;
    if (b < NBN) {
        int i = b * SB + t;
        int v = (i < N_NODES) ? dcnt[i] : 0;
        sd[t] = v;
        __syncthreads();
        for (int o = 1; o < SB; o <<= 1) {
            int x = (t >= o) ? sd[t - o] : 0;
            __syncthreads();
            sd[t] += x;
            __syncthreads();
        }
        if (i < N_NODES) dstart[i] = sd[t] - v;
        if (t == SB - 1) partials[b] = sd[t];
    } else {
        int r = b - NBN;
        int v = (t < NB) ? counts[t * R2 + r] : 0;
        sd[t] = v;
        __syncthreads();
        for (int o = 1; o < SB; o <<= 1) {
            int x = (t >= o) ? sd[t - o] : 0;
            __syncthreads();
            sd[t] += x;
            __syncthreads();
        }
        if (t < NB) basem[t * R2 + r] = sd[t] - v;
        if (t == SB - 1) total[r] = sd[t];

        // pack W1: pw1[r][lane][0..7]=B0 (col n), [8..15]=B1 (col 16+n); k=q*8+j
        const float* Wr1 = W1 + (size_t)r * (EMB * EMB);
        {
            int l = t >> 4, j = t & 15;
            int n = l & 15, q = l >> 4;
            int k = q * 8 + (j & 7);
            int col = (j < 8) ? n : (16 + n);
            pw1[(size_t)r * 1024 + t] = f2bf_u(Wr1[k * EMB + col]);
        }
        if (t < 512) {
            const float* Wr2 = W2 + (size_t)r * (EMB * TYPES);
            int l = t >> 3, j = t & 7;
            int n = l & 15, q = l >> 4;
            int k = q * 8 + j;
            pw2[(size_t)r * 512 + t] = f2bf_u(Wr2[k * TYPES + n]);
        }
    }
}

// ---------------------------------------------------------------------------
// Two independent single-block scans: block0 = relation offsets, block1 = node partials.
__global__ __launch_bounds__(256) void scanB2_kernel(const int* __restrict__ total,
                                                     int* __restrict__ off,
                                                     int* __restrict__ partials) {
    __shared__ int sd[256];
    int t = threadIdx.x;
    if (blockIdx.x == 0) {
        int v = (t < R2) ? total[t] : 0;
        sd[t] = v;
        __syncthreads();
        for (int o = 1; o < 256; o <<= 1) {
            int x = (t >= o) ? sd[t - o] : 0; __syncthreads();
            sd[t] += x; __syncthreads();
        }
        if (t < R2) off[t] = sd[t] - v;
        if (t == R2 - 1) off[R2] = sd[t];
    } else {
        int v = (t < NBN) ? partials[t] : 0;
        sd[t] = v;
        __syncthreads();
        for (int o = 1; o < 256; o <<= 1) {
            int x = (t >= o) ? sd[t - o] : 0; __syncthreads();
            sd[t] += x; __syncthreads();
        }
        if (t < NBN) partials[t] = sd[t] - v;          // exclusive, in place
    }
}

// ---------------------------------------------------------------------------
// Scatter: relpos via LDS ranks; dst slot via dcur atomic.
// One int4 store per edge: {sid, src, pdst, 0}.
__global__ __launch_bounds__(SB) void scatter_kernel(
        const int* __restrict__ edge_src, const int* __restrict__ edge_dst,
        const int* __restrict__ etype, const int* __restrict__ src_ids,
        const int* __restrict__ basem, const int* __restrict__ off,
        const int* __restrict__ dstart, const int* __restrict__ partials,
        int* __restrict__ dcur, int4* __restrict__ epack) {
    __shared__ int lh[R2];
    int t = threadIdx.x, b = blockIdx.x;
    if (t < R2) lh[t] = 0;
    __syncthreads();
    int e = b * SB + t;
    if (e >= N_EDGES) return;
    int r = etype[e];
    int rank = atomicAdd(&lh[r], 1);
    int relpos = off[r] + basem[b * R2 + r] + rank;
    int d = edge_dst[e];
    int drank = atomicAdd(&dcur[d], 1);
    int s = edge_src[e];
    int4 v = { src_ids[s], s, dstart[d] + partials[d >> 10] + drank, 0 };
    epack[relpos] = v;
}

// ---------------------------------------------------------------------------
// Layer 1: gather A-rows from L2-resident ent_bf; register B-frags; 2 MFMA/tile;
// rows stored bf16 to dst-sorted msg1 (no atomics, no LDS, no shfl).
__global__ __launch_bounds__(64) void layer1_kernel(
        const unsigned short* __restrict__ ent_bf,
        const unsigned short* __restrict__ pw1,
        const int* __restrict__ off, const int4* __restrict__ epack,
        unsigned short* __restrict__ msg1) {
    int r = blockIdx.x % R2, stripe = blockIdx.x / R2;
    int lo = off[r], hi = off[r + 1];
    int nT = (hi - lo + 15) >> 4;
    int lane = threadIdx.x;
    int n = lane & 15, q = lane >> 4;
    short8 b0 = *(const short8*)(pw1 + (size_t)r * 1024 + lane * 16);
    short8 b1 = *(const short8*)(pw1 + (size_t)r * 1024 + lane * 16 + 8);
    for (int g = stripe; g < nT; g += S1) {
        int base = lo + g * 16;
        int cl = hi - base;
        int me = n < cl ? n : cl - 1;
        int sid = epack[base + me].x;
        short8 a = *(const short8*)(ent_bf + (size_t)sid * EMB + q * 8);
        f32x4 c0 = {0.f,0.f,0.f,0.f}, c1 = {0.f,0.f,0.f,0.f};
        c0 = __builtin_amdgcn_mfma_f32_16x16x32_bf16(a, b0, c0, 0, 0, 0);
        c1 = __builtin_amdgcn_mfma_f32_16x16x32_bf16(a, b1, c1, 0, 0, 0);
#pragma unroll
        for (int i = 0; i < 4; ++i) {
            int row = q * 4 + i;
            if (row < cl) {
                int p = epack[base + row].z;
                msg1[(size_t)p * EMB + n]      = f2bf_u(c0[i]);
                msg1[(size_t)p * EMB + 16 + n] = f2bf_u(c1[i]);
            }
        }
    }
}

// ---------------------------------------------------------------------------
// Segmented mean + relu -> h1 in bf16 (u32 = 2 cols). Sums in fp32.
__global__ void reduce1_kernel(const unsigned int* __restrict__ msg1,
                               const int* __restrict__ dstart,
                               const int* __restrict__ partials,
                               const int* __restrict__ dcnt,
                               unsigned int* __restrict__ h1bf) {
    int t = blockIdx.x * blockDim.x + threadIdx.x;   // over N_NODES*16
    if (t >= N_NODES * 16) return;
    int nn = t >> 4, cp = t & 15;
    int s = dstart[nn] + partials[nn >> 10];
    int cnt = dcnt[nn];
    float sx = 0.f, sy = 0.f;
    for (int k = 0; k < cnt; ++k) {
        unsigned v = msg1[(size_t)(s + k) * 16 + cp];   // row = 16 u32
        sx += bfl(v); sy += bfh(v);
    }
    float inv = 1.0f / fmaxf((float)cnt, 1.0f);
    unsigned lo = f2bf_u(fmaxf(sx * inv, 0.f));
    unsigned hi = f2bf_u(fmaxf(sy * inv, 0.f));
    h1bf[t] = lo | (hi << 16);
}

// ---------------------------------------------------------------------------
// Layer 2: gather bf16 h1 rows (16B/lane), 1 MFMA/tile, store bf16 msg2 dst-sorted.
__global__ __launch_bounds__(64) void layer2_kernel(
        const unsigned short* __restrict__ h1bf,
        const unsigned short* __restrict__ pw2,
        const int* __restrict__ off, const int4* __restrict__ epack,
        unsigned short* __restrict__ msg2) {
    int r = blockIdx.x % R2, stripe = blockIdx.x / R2;
    int lo = off[r], hi = off[r + 1];
    int nT = (hi - lo + 15) >> 4;
    int lane = threadIdx.x;
    int n = lane & 15, q = lane >> 4;
    short8 b = *(const short8*)(pw2 + (size_t)r * 512 + lane * 8);
    for (int g = stripe; g < nT; g += S2) {
        int base = lo + g * 16;
        int cl = hi - base;
        int me = n < cl ? n : cl - 1;
        int s = epack[base + me].y;
        short8 a = *(const short8*)(h1bf + (size_t)s * EMB + q * 8);
        f32x4 c = {0.f,0.f,0.f,0.f};
        c = __builtin_amdgcn_mfma_f32_16x16x32_bf16(a, b, c, 0, 0, 0);
#pragma unroll
        for (int i = 0; i < 4; ++i) {
            int row = q * 4 + i;
            if (row < cl) {
                int p = epack[base + row].z;
                msg2[(size_t)p * TYPES + n] = f2bf_u(c[i]);
            }
        }
    }
}

// ---------------------------------------------------------------------------
// Segmented mean + PonderNet head, fused; writes final fp32 output.
__global__ void reduce2_head_kernel(const unsigned int* __restrict__ msg2,
                                    const int* __restrict__ dstart,
                                    const int* __restrict__ partials,
                                    const int* __restrict__ dcnt,
                                    const float* __restrict__ lw,
                                    const float* __restrict__ lb,
                                    float* __restrict__ out) {
    int nn = blockIdx.x * blockDim.x + threadIdx.x;
    if (nn >= N_NODES) return;
    int s = dstart[nn] + partials[nn >> 10];
    int cnt = dcnt[nn];

    float h[TYPES];
#pragma unroll
    for (int j = 0; j < TYPES; ++j) h[j] = 0.f;
    for (int k = 0; k < cnt; ++k) {
        const uint4* row = (const uint4*)(msg2 + (size_t)(s + k) * 8);  // 16 bf16 = 8 u32
        uint4 A = row[0], B = row[1];
        h[0] += bfl(A.x);  h[1] += bfh(A.x);  h[2] += bfl(A.y);  h[3] += bfh(A.y);
        h[4] += bfl(A.z);  h[5] += bfh(A.z);  h[6] += bfl(A.w);  h[7] += bfh(A.w);
        h[8] += bfl(B.x);  h[9] += bfh(B.x);  h[10] += bfl(B.y); h[11] += bfh(B.y);
        h[12] += bfl(B.z); h[13] += bfh(B.z); h[14] += bfl(B.w); h[15] += bfh(B.w);
    }
    float inv = 1.0f / fmaxf((float)cnt, 1.0f);
    float dot = 0.f;
#pragma unroll
    for (int j = 0; j < TYPES; ++j) { h[j] *= inv; dot += h[j] * lw[j]; }
    dot += lb[0];
    float lam = 1.0f / (1.0f + expf(-dot));

    float4* y0 = (float4*)(out + (size_t)nn * TYPES);
    float4* y1 = (float4*)(out + (size_t)N_NODES * TYPES + (size_t)nn * TYPES);
#pragma unroll
    for (int j = 0; j < 4; ++j) {
        float4 v = { h[4*j], h[4*j+1], h[4*j+2], h[4*j+3] };
        y0[j] = v; y1[j] = v;
    }
    out[(size_t)2 * N_NODES * TYPES + nn] = lam;
    out[(size_t)2 * N_NODES * TYPES + N_NODES + nn] = 1.0f - lam;
}

// ---------------------------------------------------------------------------
extern "C" void kernel_launch(void* const* d_in, const int* in_sizes, int n_in,
                              void* d_out, int out_size, void* d_ws, size_t ws_size,
                              hipStream_t stream) {
    const float* entity = (const float*)d_in[0];
    const float* W1     = (const float*)d_in[1];
    const float* W2     = (const float*)d_in[2];
    const float* lw     = (const float*)d_in[3];
    const float* lb     = (const float*)d_in[4];
    const int* src_ids  = (const int*)d_in[5];
    const int* edge_src = (const int*)d_in[6];
    const int* edge_dst = (const int*)d_in[7];
    const int* etype    = (const int*)d_in[8];
    float* out = (float*)d_out;

    // ws layout (u32 units, 16B aligned)
    unsigned int* W = (unsigned int*)d_ws;
    int* dcnt      = (int*)(W + 0);            // 100000   (zeroed)
    int* dcur      = (int*)(W + 100000);       // 100000   (zeroed)
    int* dstart    = (int*)(W + 200000);       // 100008
    int* partials  = (int*)(W + 300008);       // 128
    int* counts    = (int*)(W + 300136);       // 24500
    int* basem     = (int*)(W + 324636);       // 24500
    int* total     = (int*)(W + 349136);       // 128
    int* off       = (int*)(W + 349264);       // 144 (pad to 16B align)
    int4* epack    = (int4*)(W + 349408);      // 250000 int4 = 1M u32
    unsigned short* ent_bf = (unsigned short*)(W + 1349408); // 1.6M u32
    unsigned short* pw1    = (unsigned short*)(W + 2949408); // 51200 u32
    unsigned short* pw2    = (unsigned short*)(W + 3000608); // 25600 u32
    unsigned int* msg1     = (unsigned int*)(W + 3026208);   // 4M u32 (bf16 msgs)
    unsigned int* h1bf     = (unsigned int*)(W + 7026208);   // 1.6M u32
    unsigned int* msg2     = (unsigned int*)(W + 8626208);   // 2M u32  -> ~42.5 MB

    (void)hipMemsetAsync(d_ws, 0, 200000 * sizeof(int), stream);   // dcnt + dcur

    hist_conv_kernel<<<NB, SB, 0, stream>>>(etype, edge_dst, entity,
                                            counts, dcnt, ent_bf);
    scan_fused_kernel<<<NBN + R2, SB, 0, stream>>>(dcnt, dstart, partials,
                                                   counts, basem, total,
                                                   W1, W2, pw1, pw2);
    scanB2_kernel<<<2, 256, 0, stream>>>(total, off, partials);
    scatter_kernel<<<NB, SB, 0, stream>>>(edge_src, edge_dst, etype, src_ids,
                                          basem, off, dstart, partials, dcur, epack);
    layer1_kernel<<<R2 * S1, 64, 0, stream>>>(ent_bf, pw1, off, epack,
                                              (unsigned short*)msg1);
    reduce1_kernel<<<(N_NODES * 16 + 255) / 256, 256, 0, stream>>>(
        msg1, dstart, partials, dcnt, h1bf);
    layer2_kernel<<<R2 * S2, 64, 0, stream>>>((const unsigned short*)h1bf, pw2,
                                              off, epack, (unsigned short*)msg2);
    reduce2_head_kernel<<<(N_NODES + 255) / 256, 256, 0, stream>>>(
        msg2, dstart, partials, dcnt, lw, lb, out);
}